// Round 16
// baseline (47.030 us; speedup 1.0000x reference)
//
#include <hip/hip_runtime.h>
#include <math.h>

#define N 4096
#define BSZ 2048
#define D 128
#define NLAB 100
#define LOG2E 1.4426950408889634f

// float offsets in ws
#define OFF_M   0
#define OFF_S1  N
#define OFF_ACC (2 * N)
#define OFF_CNT (2 * N + 1)
// int offsets
#define IOFF_H  (2 * N + 8)                 // hist[100]
#define IOFF_B  (2 * N + 128)               // bucket[100][64]
#define OFF_CF  (2 * N + 128 + NLAB * 64)   // bf16 cf[N][D] from here (16B aligned)

typedef __bf16 bf16x8 __attribute__((ext_vector_type(8)));
typedef float f32x4 __attribute__((ext_vector_type(4)));
typedef unsigned short u16x8 __attribute__((ext_vector_type(8)));

__device__ __forceinline__ int rowbase(int i) {
    return (i & (BSZ - 1)) * (2 * D) + (i >> 11) * D;
}
__device__ __forceinline__ unsigned short f2bf(float x) {
    unsigned u = __float_as_uint(x);
    return (unsigned short)((u + 0x7fffu + ((u >> 16) & 1u)) >> 16);  // RNE
}
__device__ __forceinline__ float bf2f(unsigned short u) {
    return __uint_as_float((unsigned)u << 16);
}

// init: bf16 convert + fp32 diag (rowmax) + zero S1/ACC/CNT; block 0 builds hist+buckets
__global__ void init_kernel(const float* __restrict__ feat, const int* __restrict__ labels,
                            float* __restrict__ ws, unsigned short* __restrict__ cf) {
    int t = threadIdx.x;
    int row = blockIdx.x * 16 + (t >> 4);
    int lq = t & 15;
    const float* p = feat + rowbase(row) + lq * 8;
    float4 v0 = *(const float4*)(p);
    float4 v1 = *(const float4*)(p + 4);
    float dot = v0.x * v0.x + v0.y * v0.y + v0.z * v0.z + v0.w * v0.w
              + v1.x * v1.x + v1.y * v1.y + v1.z * v1.z + v1.w * v1.w;
#pragma unroll
    for (int off = 1; off < 16; off <<= 1) dot += __shfl_xor(dot, off);

    u16x8 u;
    u[0] = f2bf(v0.x); u[1] = f2bf(v0.y); u[2] = f2bf(v0.z); u[3] = f2bf(v0.w);
    u[4] = f2bf(v1.x); u[5] = f2bf(v1.y); u[6] = f2bf(v1.z); u[7] = f2bf(v1.w);
    *(u16x8*)(cf + row * D + lq * 8) = u;

    if (lq == 0) {
        ws[OFF_M + row] = fminf(fmaxf(dot, -1.f), 1.f);  // rowmax = clipped fp32 diag
        ws[OFF_S1 + row] = 0.f;
    }
    if (blockIdx.x == 0) {
        int* histI = (int*)ws + IOFF_H;
        int* bucket = (int*)ws + IOFF_B;
        if (t < NLAB) histI[t] = 0;
        if (t == 0) {
            ws[OFF_ACC] = 0.f;
            ((unsigned int*)ws)[OFF_CNT] = 0u;
        }
        __syncthreads();
#pragma unroll
        for (int r = 0; r < 8; ++r) {
            int b = r * 256 + t;
            int lab = labels[b];
            int slot = atomicAdd(&histI[lab], 1);
            if (slot < 64) bucket[lab * 64 + slot] = b;
        }
    }
}

// 1024 blocks x 256: R12 staging/MFMA; uniform neg-path epilogue via angle addition
__launch_bounds__(256)
__global__ void pair_kernel(const unsigned short* __restrict__ cf,
                            const int* __restrict__ labels, float* __restrict__ ws) {
    __shared__ unsigned short Abuf[128 * 64];
    __shared__ unsigned short Bbuf[128 * 64];
    __shared__ float labIf[128], labJf[128];

    const int t = threadIdx.x;
    const int bi = blockIdx.x >> 5;
    const int bj = blockIdx.x & 31;
    const int i0 = bi * 128, j0 = bj * 128;

    if (t < 128) labIf[t] = (float)labels[(i0 + t) & (BSZ - 1)];
    else         labJf[t - 128] = (float)labels[(j0 + (t - 128)) & (BSZ - 1)];

    const int wid = t >> 6, lane = t & 63;
    const int wp = wid >> 1, wq = wid & 1;
    const int lrow = lane & 15;
    const int srow = t >> 3;
    const int scc = t & 7;

    f32x4 acc[4][4] = {};

#pragma unroll
    for (int p = 0; p < 2; ++p) {
        u16x8 ra[4], rb[4];
#pragma unroll
        for (int it = 0; it < 4; ++it) {
            int row = it * 32 + srow;
            ra[it] = *(const u16x8*)(cf + (size_t)(j0 + row) * D + p * 64 + scc * 8);
            rb[it] = *(const u16x8*)(cf + (size_t)(i0 + row) * D + p * 64 + scc * 8);
        }
        if (p) __syncthreads();
#pragma unroll
        for (int it = 0; it < 4; ++it) {
            int row = it * 32 + srow;
            int sl = scc ^ (row & 7);
            *(u16x8*)(Abuf + row * 64 + sl * 8) = ra[it];
            *(u16x8*)(Bbuf + row * 64 + sl * 8) = rb[it];
        }
        __syncthreads();

#pragma unroll
        for (int k2 = 0; k2 < 2; ++k2) {
            const int ccf = k2 * 4 + (lane >> 4);
            const int sa = (ccf ^ (lrow & 7)) * 8;
            bf16x8 a[4], b[4];
#pragma unroll
            for (int r = 0; r < 4; ++r)
                a[r] = *(const bf16x8*)(Abuf + (wq * 64 + r * 16 + lrow) * 64 + sa);
#pragma unroll
            for (int c = 0; c < 4; ++c)
                b[c] = *(const bf16x8*)(Bbuf + (wp * 64 + c * 16 + lrow) * 64 + sa);
#pragma unroll
            for (int r = 0; r < 4; ++r)
#pragma unroll
                for (int c = 0; c < 4; ++c)
                    acc[r][c] = __builtin_amdgcn_mfma_f32_16x16x32_bf16(a[r], b[c], acc[r][c], 0, 0, 0);
        }
    }

    // per-ac I-row constants: Ac = -log2e*cos(li/200 rev), As = -log2e*sin(li/200 rev)
    float Ac[4], As[4];
#pragma unroll
    for (int ac = 0; ac < 4; ++ac) {
        float reva = labIf[wp * 64 + ac * 16 + lrow] * 0.005f;
        Ac[ac] = -LOG2E * __builtin_amdgcn_cosf(reva);
        As[ac] = -LOG2E * __builtin_amdgcn_sinf(reva);
    }

    const int jbl = wq * 64 + ((lane >> 4) << 2);
    float s1v[4] = {0.f, 0.f, 0.f, 0.f};

#pragma unroll
    for (int ar = 0; ar < 4; ++ar) {
        // 4 consecutive J labels for this fragment
        float4 ljf = *(const float4*)&labJf[jbl + ar * 16];
        float cb[4], sb[4];
#pragma unroll
        for (int rg = 0; rg < 4; ++rg) {
            float revb = ((const float*)&ljf)[rg] * 0.005f;
            cb[rg] = __builtin_amdgcn_cosf(revb);
            sb[rg] = __builtin_amdgcn_sinf(revb);
        }
#pragma unroll
        for (int ac = 0; ac < 4; ++ac) {
#pragma unroll
            for (int rg = 0; rg < 4; ++rg) {
                float c = __builtin_amdgcn_fmed3f(acc[ar][ac][rg], -1.f, 1.f);
                float t1 = As[ac] * sb[rg];
                float cph = fmaf(Ac[ac], cb[rg], t1);            // log2e-scaled -cos(phi)... sign folded
                float t2 = Ac[ac] * sb[rg];
                float sph = fmaf(As[ac], cb[rg], -t2);           // |sph| = log2e*|sin(phi)|
                float st = __builtin_amdgcn_sqrtf(fmaf(-c, c, 1.000001f));
                float tmp = st * __builtin_fabsf(sph);
                float nl2 = fmaf(c, cph, -tmp);                  // neg_logit * log2e
                s1v[ac] += __builtin_amdgcn_exp2f(nl2);
            }
        }
    }

#pragma unroll
    for (int ac = 0; ac < 4; ++ac) {
        const int gi = i0 + wp * 64 + ac * 16 + lrow;
        float s1 = s1v[ac];
        s1 += __shfl_xor(s1, 16); s1 += __shfl_xor(s1, 32);
        if (lane < 16) atomicAdd(&ws[OFF_S1 + gi], s1);
    }
}

// 512 blocks x 512 threads: one wave per row; sparse positive corrections + loss
__launch_bounds__(512)
__global__ void final_kernel(const unsigned short* __restrict__ cf,
                             const int* __restrict__ labels,
                             float* __restrict__ ws, float* __restrict__ out) {
    __shared__ float red[8];
    const int t = threadIdx.x;
    const int wid = t >> 6, lane = t & 63;
    const int i = blockIdx.x * 8 + wid;

    const int lab = labels[i & (BSZ - 1)];
    const int* histI = (const int*)ws + IOFF_H;
    const int* bucket = (const int*)ws + IOFF_B;
    const int h = min(histI[lab], 64);
    const float m = ws[OFF_M + i];
    const unsigned short* ci = cf + (size_t)i * D;

    float pc = 0.f, scv = 0.f;
#pragma unroll
    for (int base = 0; base < 128; base += 64) {
        int l = base + lane;
        if (l < 2 * h) {
            int b = bucket[lab * 64 + (l >> 1)];
            int j = ((l & 1) << 11) + b;
            const unsigned short* cj = cf + (size_t)j * D;
            float dot = 0.f;
#pragma unroll
            for (int k = 0; k < 16; ++k) {
                u16x8 A = *(const u16x8*)(ci + k * 8);
                u16x8 B = *(const u16x8*)(cj + k * 8);
#pragma unroll
                for (int e = 0; e < 8; ++e)
                    dot = fmaf(bf2f(A[e]), bf2f(B[e]), dot);
            }
            float c = __builtin_amdgcn_fmed3f(dot, -1.f, 1.f);
            float em = __expf(-c);            // uniform neg term at dist=0
            if (j == i) {
                pc -= em;                     // remove diagonal's neg term
            } else {
                pc += __expf(c - m) - em;     // positive: swap neg -> logits
                scv += c;
            }
        }
    }
#pragma unroll
    for (int off = 1; off < 64; off <<= 1) {
        pc += __shfl_xor(pc, off);
        scv += __shfl_xor(scv, off);
    }

    if (lane == 0) {
        float ct = 2.f * (float)h - 1.f;
        float S1 = ws[OFF_S1 + i] + pc;
        float lp = scv - ct * m - ct * __logf(S1);
        red[wid] = (lp + 1e-6f) / (ct + 1e-6f);
    }
    __syncthreads();

    if (t == 0) {
        float bsum = 0.f;
#pragma unroll
        for (int w = 0; w < 8; ++w) bsum += red[w];
        atomicAdd(&ws[OFF_ACC], bsum);
        __threadfence();
        unsigned int old = atomicAdd(&((unsigned int*)ws)[OFF_CNT], 1u);
        if (old == 511u) {
            float total = __hip_atomic_load(&ws[OFF_ACC], __ATOMIC_ACQUIRE,
                                            __HIP_MEMORY_SCOPE_AGENT);
            out[0] = -total / (float)N;
        }
    }
}

extern "C" void kernel_launch(void* const* d_in, const int* in_sizes, int n_in,
                              void* d_out, int out_size, void* d_ws, size_t ws_size,
                              hipStream_t stream) {
    const float* feat = (const float*)d_in[0];
    const int* labels = (const int*)d_in[1];
    float* ws = (float*)d_ws;
    unsigned short* cf = (unsigned short*)(ws + OFF_CF);
    float* out = (float*)d_out;

    init_kernel<<<N / 16, 256, 0, stream>>>(feat, labels, ws, cf);
    pair_kernel<<<1024, 256, 0, stream>>>(cf, labels, ws);
    final_kernel<<<512, 512, 0, stream>>>(cf, labels, ws, out);
}

// Round 17
// 30.228 us; speedup vs baseline: 1.5559x; 1.5559x over previous
//
#include <hip/hip_runtime.h>
#include <math.h>

#define N 4096
#define BSZ 2048
#define D 128
#define LOG2E 1.4426950408889634f

typedef __bf16 bf16x8 __attribute__((ext_vector_type(8)));
typedef float f32x4 __attribute__((ext_vector_type(4)));
typedef unsigned short u16x8 __attribute__((ext_vector_type(8)));

// cf[i] = features[i % bsz, i / bsz, :]  (view-major stacking)
__device__ __forceinline__ int rowbase(int i) {
    return (i & (BSZ - 1)) * (2 * D) + (i >> 11) * D;
}
__device__ __forceinline__ unsigned short f2bf(float x) {
    unsigned u = __float_as_uint(x);
    return (unsigned short)((u + 0x7fffu + ((u >> 16) & 1u)) >> 16);  // RNE
}

// ws layout (floats): m[0..N) S1[N..2N) sumc[2N..3N) cnt[3N..4N)
//                     [4N]=loss accum, [4N+1]=block counter (u32); cf at 4N+16
__global__ void init_kernel(const float* __restrict__ feat, float* __restrict__ ws,
                            unsigned short* __restrict__ cf) {
    int t = threadIdx.x;
    int row = blockIdx.x * 16 + (t >> 4);
    int lq = t & 15;
    const float* p = feat + rowbase(row) + lq * 8;
    float4 v0 = *(const float4*)(p);
    float4 v1 = *(const float4*)(p + 4);
    float dot = v0.x * v0.x + v0.y * v0.y + v0.z * v0.z + v0.w * v0.w
              + v1.x * v1.x + v1.y * v1.y + v1.z * v1.z + v1.w * v1.w;
#pragma unroll
    for (int off = 1; off < 16; off <<= 1) dot += __shfl_xor(dot, off);

    u16x8 u;
    u[0] = f2bf(v0.x); u[1] = f2bf(v0.y); u[2] = f2bf(v0.z); u[3] = f2bf(v0.w);
    u[4] = f2bf(v1.x); u[5] = f2bf(v1.y); u[6] = f2bf(v1.z); u[7] = f2bf(v1.w);
    *(u16x8*)(cf + row * D + lq * 8) = u;

    if (lq == 0) {
        ws[row] = fminf(fmaxf(dot, -1.f), 1.f);  // rowmax = clipped diagonal
        ws[N + row] = 0.f;
        ws[2 * N + row] = 0.f;
        ws[3 * N + row] = 0.f;
    }
    if (blockIdx.x == 0 && t == 0) {
        ws[4 * N] = 0.f;                          // loss accumulator
        ((unsigned int*)ws)[4 * N + 1] = 0u;      // final-block counter
    }
}

// 1024 blocks x 256: R12 staging/MFMA; epilogue trans ops cut via angle addition
__launch_bounds__(256)
__global__ void pair_kernel(const unsigned short* __restrict__ cf,
                            const int* __restrict__ labels, float* __restrict__ ws) {
    __shared__ unsigned short Abuf[128 * 64];
    __shared__ unsigned short Bbuf[128 * 64];
    __shared__ float labIf[128], labJf[128], mI[128];

    const int t = threadIdx.x;
    const int bi = blockIdx.x >> 5;
    const int bj = blockIdx.x & 31;
    const int i0 = bi * 128, j0 = bj * 128;

    if (t < 128) {
        labIf[t] = (float)labels[(i0 + t) & (BSZ - 1)];
        mI[t] = ws[i0 + t];
    } else {
        int u = t - 128;
        labJf[u] = (float)labels[(j0 + u) & (BSZ - 1)];
    }

    const int wid = t >> 6, lane = t & 63;
    const int wp = wid >> 1, wq = wid & 1;
    const int lrow = lane & 15;
    const int srow = t >> 3;
    const int scc = t & 7;

    f32x4 acc[4][4] = {};

#pragma unroll
    for (int p = 0; p < 2; ++p) {
        u16x8 ra[4], rb[4];
#pragma unroll
        for (int it = 0; it < 4; ++it) {
            int row = it * 32 + srow;
            ra[it] = *(const u16x8*)(cf + (size_t)(j0 + row) * D + p * 64 + scc * 8);
            rb[it] = *(const u16x8*)(cf + (size_t)(i0 + row) * D + p * 64 + scc * 8);
        }
        if (p) __syncthreads();
#pragma unroll
        for (int it = 0; it < 4; ++it) {
            int row = it * 32 + srow;
            int sl = scc ^ (row & 7);
            *(u16x8*)(Abuf + row * 64 + sl * 8) = ra[it];
            *(u16x8*)(Bbuf + row * 64 + sl * 8) = rb[it];
        }
        __syncthreads();

#pragma unroll
        for (int k2 = 0; k2 < 2; ++k2) {
            const int ccf = k2 * 4 + (lane >> 4);
            const int sa = (ccf ^ (lrow & 7)) * 8;
            bf16x8 a[4], b[4];
#pragma unroll
            for (int r = 0; r < 4; ++r)
                a[r] = *(const bf16x8*)(Abuf + (wq * 64 + r * 16 + lrow) * 64 + sa);
#pragma unroll
            for (int c = 0; c < 4; ++c)
                b[c] = *(const bf16x8*)(Bbuf + (wp * 64 + c * 16 + lrow) * 64 + sa);
#pragma unroll
            for (int r = 0; r < 4; ++r)
#pragma unroll
                for (int c = 0; c < 4; ++c)
                    acc[r][c] = __builtin_amdgcn_mfma_f32_16x16x32_bf16(a[r], b[c], acc[r][c], 0, 0, 0);
        }
    }

    // per-ac I-row constants (angle addition, log2e folded):
    // Ac = -L*cos(li/200 rev), As = -L*sin(li/200 rev), Lm = L*m
    const bool hasDiag = (bi == bj);
    float Ac[4], As[4], Lm[4], li4[4];
    int dg4[4];
#pragma unroll
    for (int ac = 0; ac < 4; ++ac) {
        const int ri = wp * 64 + ac * 16 + lrow;
        li4[ac] = labIf[ri];
        float reva = li4[ac] * 0.005f;
        Ac[ac] = -LOG2E * __builtin_amdgcn_cosf(reva);
        As[ac] = -LOG2E * __builtin_amdgcn_sinf(reva);
        Lm[ac] = LOG2E * mI[ri];
    }
    const int jbl = wq * 64 + ((lane >> 4) << 2);
#pragma unroll
    for (int ac = 0; ac < 4; ++ac)
        dg4[ac] = hasDiag ? ((wp * 64 + ac * 16 + lrow) - jbl) : -1;

    float s1v[4] = {0.f, 0.f, 0.f, 0.f};
    float scv[4] = {0.f, 0.f, 0.f, 0.f};
    float ctv[4] = {0.f, 0.f, 0.f, 0.f};

#pragma unroll
    for (int ar = 0; ar < 4; ++ar) {
        float ljv[4], cb[4], sb[4];
#pragma unroll
        for (int rg = 0; rg < 4; ++rg) {
            ljv[rg] = labJf[jbl + ar * 16 + rg];
            float revb = ljv[rg] * 0.005f;
            cb[rg] = __builtin_amdgcn_cosf(revb);
            sb[rg] = __builtin_amdgcn_sinf(revb);
        }
#pragma unroll
        for (int ac = 0; ac < 4; ++ac) {
#pragma unroll
            for (int rg = 0; rg < 4; ++rg) {
                float c = __builtin_amdgcn_fmed3f(acc[ar][ac][rg], -1.f, 1.f);
                // L*cos(phi) and L*|sin(phi)| via angle addition (R16-verified algebra)
                float cph = fmaf(Ac[ac], cb[rg], As[ac] * sb[rg]);
                float sph = fmaf(As[ac], cb[rg], -(Ac[ac] * sb[rg]));
                float st = __builtin_amdgcn_sqrtf(fmaf(-c, c, 1.000001f));
                float nl2 = fmaf(c, cph, -st * __builtin_fabsf(sph));  // L*neg_logit
                bool pos = (li4[ac] == ljv[rg]);
                bool diag = (dg4[ac] == ar * 16 + rg);
                float logit2 = pos ? fmaf(LOG2E, c, -Lm[ac]) : nl2;    // L*logit
                float e = diag ? 0.f : __builtin_amdgcn_exp2f(logit2);
                float pf = (pos && !diag) ? 1.f : 0.f;
                s1v[ac] += e;
                scv[ac] = fmaf(pf, c, scv[ac]);
                ctv[ac] += pf;
            }
        }
    }

#pragma unroll
    for (int ac = 0; ac < 4; ++ac) {
        const int gi = i0 + wp * 64 + ac * 16 + lrow;
        float s1 = s1v[ac], sc = scv[ac], ct = ctv[ac];
        s1 += __shfl_xor(s1, 16); s1 += __shfl_xor(s1, 32);
        sc += __shfl_xor(sc, 16); sc += __shfl_xor(sc, 32);
        ct += __shfl_xor(ct, 16); ct += __shfl_xor(ct, 32);
        if (lane < 16) {
            atomicAdd(&ws[N + gi], s1);
            atomicAdd(&ws[2 * N + gi], sc);
            atomicAdd(&ws[3 * N + gi], ct);
        }
    }
}

// 16 blocks x 256 threads: one row per thread; last block writes the scalar out
__global__ void final_kernel(float* __restrict__ ws, float* __restrict__ out) {
    __shared__ float red[4];
    const int t = threadIdx.x;
    const int i = blockIdx.x * 256 + t;

    float ct = ws[3 * N + i];
    float lp = ws[2 * N + i] - ct * ws[i] - ct * __logf(ws[N + i]);
    float v = (lp + 1e-6f) / (ct + 1e-6f);
#pragma unroll
    for (int off = 1; off < 64; off <<= 1) v += __shfl_xor(v, off);
    if ((t & 63) == 0) red[t >> 6] = v;
    __syncthreads();

    if (t == 0) {
        float bsum = red[0] + red[1] + red[2] + red[3];
        atomicAdd(&ws[4 * N], bsum);
        __threadfence();
        unsigned int old = atomicAdd(&((unsigned int*)ws)[4 * N + 1], 1u);
        if (old == 15u) {
            float total = __hip_atomic_load(&ws[4 * N], __ATOMIC_ACQUIRE,
                                            __HIP_MEMORY_SCOPE_AGENT);
            out[0] = -total / (float)N;
        }
    }
}

extern "C" void kernel_launch(void* const* d_in, const int* in_sizes, int n_in,
                              void* d_out, int out_size, void* d_ws, size_t ws_size,
                              hipStream_t stream) {
    const float* feat = (const float*)d_in[0];
    const int* labels = (const int*)d_in[1];
    float* ws = (float*)d_ws;
    unsigned short* cf = (unsigned short*)((float*)d_ws + 4 * N + 16);
    float* out = (float*)d_out;

    init_kernel<<<N / 16, 256, 0, stream>>>(feat, ws, cf);
    pair_kernel<<<1024, 256, 0, stream>>>(cf, labels, ws);
    final_kernel<<<16, 256, 0, stream>>>(ws, out);
}

// Round 18
// 28.880 us; speedup vs baseline: 1.6285x; 1.0467x over previous
//
#include <hip/hip_runtime.h>
#include <math.h>

#define N 4096
#define BSZ 2048
#define D 128

typedef __bf16 bf16x8 __attribute__((ext_vector_type(8)));
typedef float f32x4 __attribute__((ext_vector_type(4)));
typedef unsigned short u16x8 __attribute__((ext_vector_type(8)));

// cf[i] = features[i % bsz, i / bsz, :]  (view-major stacking)
__device__ __forceinline__ int rowbase(int i) {
    return (i & (BSZ - 1)) * (2 * D) + (i >> 11) * D;
}
__device__ __forceinline__ unsigned short f2bf(float x) {
    unsigned u = __float_as_uint(x);
    return (unsigned short)((u + 0x7fffu + ((u >> 16) & 1u)) >> 16);  // RNE
}

// ws layout (floats): m[0..N) S1[N..2N) sumc[2N..3N) cnt[3N..4N)
//                     [4N]=loss accum, [4N+1]=block counter (u32); cf at 4N+16
__global__ void init_kernel(const float* __restrict__ feat, float* __restrict__ ws,
                            unsigned short* __restrict__ cf) {
    int t = threadIdx.x;
    int row = blockIdx.x * 16 + (t >> 4);
    int lq = t & 15;
    const float* p = feat + rowbase(row) + lq * 8;
    float4 v0 = *(const float4*)(p);
    float4 v1 = *(const float4*)(p + 4);
    float dot = v0.x * v0.x + v0.y * v0.y + v0.z * v0.z + v0.w * v0.w
              + v1.x * v1.x + v1.y * v1.y + v1.z * v1.z + v1.w * v1.w;
#pragma unroll
    for (int off = 1; off < 16; off <<= 1) dot += __shfl_xor(dot, off);

    u16x8 u;
    u[0] = f2bf(v0.x); u[1] = f2bf(v0.y); u[2] = f2bf(v0.z); u[3] = f2bf(v0.w);
    u[4] = f2bf(v1.x); u[5] = f2bf(v1.y); u[6] = f2bf(v1.z); u[7] = f2bf(v1.w);
    *(u16x8*)(cf + row * D + lq * 8) = u;

    if (lq == 0) {
        ws[row] = fminf(fmaxf(dot, -1.f), 1.f);  // rowmax = clipped diagonal
        ws[N + row] = 0.f;
        ws[2 * N + row] = 0.f;
        ws[3 * N + row] = 0.f;
    }
    if (blockIdx.x == 0 && t == 0) {
        ws[4 * N] = 0.f;                          // loss accumulator
        ((unsigned int*)ws)[4 * N + 1] = 0u;      // final-block counter
    }
}

// 1024 blocks x 256 threads: 128x128 tiles; LDS-staged K-halves (XOR-swizzled)
__launch_bounds__(256)
__global__ void pair_kernel(const unsigned short* __restrict__ cf,
                            const int* __restrict__ labels, float* __restrict__ ws) {
    __shared__ unsigned short Abuf[128 * 64];   // J-tile K-half, slot = cc ^ (row&7)
    __shared__ unsigned short Bbuf[128 * 64];   // I-tile K-half
    __shared__ float labIf[128], labJf[128], mI[128];

    const int t = threadIdx.x;
    const int bi = blockIdx.x >> 5;   // 32x32 grid of 128x128 tiles
    const int bj = blockIdx.x & 31;
    const int i0 = bi * 128, j0 = bj * 128;

    if (t < 128) {
        labIf[t] = (float)labels[(i0 + t) & (BSZ - 1)];
        mI[t] = ws[i0 + t];
    } else {
        int u = t - 128;
        labJf[u] = (float)labels[(j0 + u) & (BSZ - 1)];
    }

    const int wid = t >> 6, lane = t & 63;
    const int wp = wid >> 1, wq = wid & 1;      // wp: I half, wq: J half
    const int lrow = lane & 15;

    const int srow = t >> 3;        // staging row within 32-row group
    const int scc = t & 7;          // staging col chunk (16B units)

    f32x4 acc[4][4] = {};   // [ar: J fragment][ac: I fragment]

#pragma unroll
    for (int p = 0; p < 2; ++p) {
        // ---- stage K-half p of both tiles (coalesced global -> swizzled LDS) ----
        u16x8 ra[4], rb[4];
#pragma unroll
        for (int it = 0; it < 4; ++it) {
            int row = it * 32 + srow;
            ra[it] = *(const u16x8*)(cf + (size_t)(j0 + row) * D + p * 64 + scc * 8);
            rb[it] = *(const u16x8*)(cf + (size_t)(i0 + row) * D + p * 64 + scc * 8);
        }
        if (p) __syncthreads();     // phase-0 compute must finish before overwrite
#pragma unroll
        for (int it = 0; it < 4; ++it) {
            int row = it * 32 + srow;
            int sl = scc ^ (row & 7);
            *(u16x8*)(Abuf + row * 64 + sl * 8) = ra[it];
            *(u16x8*)(Bbuf + row * 64 + sl * 8) = rb[it];
        }
        __syncthreads();

        // ---- fragments from LDS + MFMA ----
#pragma unroll
        for (int k2 = 0; k2 < 2; ++k2) {
            const int ccf = k2 * 4 + (lane >> 4);
            const int sa = (ccf ^ (lrow & 7)) * 8;   // row&7 == lrow&7 for all frags
            bf16x8 a[4], b[4];
#pragma unroll
            for (int r = 0; r < 4; ++r)
                a[r] = *(const bf16x8*)(Abuf + (wq * 64 + r * 16 + lrow) * 64 + sa);
#pragma unroll
            for (int c = 0; c < 4; ++c)
                b[c] = *(const bf16x8*)(Bbuf + (wp * 64 + c * 16 + lrow) * 64 + sa);
#pragma unroll
            for (int r = 0; r < 4; ++r)
#pragma unroll
                for (int c = 0; c < 4; ++c)
                    acc[r][c] = __builtin_amdgcn_mfma_f32_16x16x32_bf16(a[r], b[c], acc[r][c], 0, 0, 0);
        }
    }

    // per-lane J labels (float): jr_local = wq*64 + ar*16 + (lane>>4)*4 + rg
    const int jbl = wq * 64 + ((lane >> 4) << 2);
    float lj[16];
#pragma unroll
    for (int ar = 0; ar < 4; ++ar)
#pragma unroll
        for (int rg = 0; rg < 4; ++rg)
            lj[ar * 4 + rg] = labJf[jbl + ar * 16 + rg];

    const bool hasDiag = (bi == bj);

#pragma unroll
    for (int ac = 0; ac < 4; ++ac) {
        const int ri = wp * 64 + ac * 16 + lrow;   // I index (lane-local)
        const int gi = i0 + ri;
        const float li = labIf[ri];
        const float m = mI[ri];
        const int dg = hasDiag ? (ri - jbl) : -1;  // diag when dg == ar*16+rg
        float s1 = 0.f, sc = 0.f, ct = 0.f;
#pragma unroll
        for (int ar = 0; ar < 4; ++ar) {
#pragma unroll
            for (int rg = 0; rg < 4; ++rg) {
                float c = __builtin_amdgcn_fmed3f(acc[ar][ac][rg], -1.f, 1.f);
                float distf = li - lj[ar * 4 + rg];
                // phi = (1 - dist/100)*pi rad -> rev = 0.5 - dist/200 in [0.005,0.995]
                float rev = fmaf(distf, -0.005f, 0.5f);
                float cph = __builtin_amdgcn_cosf(rev);
                float sph = __builtin_fabsf(__builtin_amdgcn_sinf(rev));
                float st = __builtin_amdgcn_sqrtf(fmaf(-c, c, 1.000001f));
                float nl = fmaf(c, cph, -st * sph);
                bool pos = (distf == 0.f);
                bool diag = (dg == ar * 16 + rg);
                float logit = pos ? (c - m) : nl;
                float e = diag ? 0.f : __expf(logit);
                float pf = (pos && !diag) ? 1.f : 0.f;
                s1 += e;
                sc = fmaf(pf, c, sc);
                ct += pf;
            }
        }
        // combine the 4 lane-groups that share gi (lane&15): xor 16, then 32
        s1 += __shfl_xor(s1, 16); s1 += __shfl_xor(s1, 32);
        sc += __shfl_xor(sc, 16); sc += __shfl_xor(sc, 32);
        ct += __shfl_xor(ct, 16); ct += __shfl_xor(ct, 32);
        if (lane < 16) {
            atomicAdd(&ws[N + gi], s1);
            atomicAdd(&ws[2 * N + gi], sc);
            atomicAdd(&ws[3 * N + gi], ct);
        }
    }
}

// 16 blocks x 256 threads: one row per thread; last block writes the scalar out
__global__ void final_kernel(float* __restrict__ ws, float* __restrict__ out) {
    __shared__ float red[4];
    const int t = threadIdx.x;
    const int i = blockIdx.x * 256 + t;

    float ct = ws[3 * N + i];
    float lp = ws[2 * N + i] - ct * ws[i] - ct * __logf(ws[N + i]);
    float v = (lp + 1e-6f) / (ct + 1e-6f);
#pragma unroll
    for (int off = 1; off < 64; off <<= 1) v += __shfl_xor(v, off);
    if ((t & 63) == 0) red[t >> 6] = v;
    __syncthreads();

    if (t == 0) {
        float bsum = red[0] + red[1] + red[2] + red[3];
        atomicAdd(&ws[4 * N], bsum);
        __threadfence();
        unsigned int old = atomicAdd(&((unsigned int*)ws)[4 * N + 1], 1u);
        if (old == 15u) {
            float total = __hip_atomic_load(&ws[4 * N], __ATOMIC_ACQUIRE,
                                            __HIP_MEMORY_SCOPE_AGENT);
            out[0] = -total / (float)N;
        }
    }
}

extern "C" void kernel_launch(void* const* d_in, const int* in_sizes, int n_in,
                              void* d_out, int out_size, void* d_ws, size_t ws_size,
                              hipStream_t stream) {
    const float* feat = (const float*)d_in[0];
    const int* labels = (const int*)d_in[1];
    float* ws = (float*)d_ws;
    unsigned short* cf = (unsigned short*)((float*)d_ws + 4 * N + 16);
    float* out = (float*)d_out;

    init_kernel<<<N / 16, 256, 0, stream>>>(feat, ws, cf);
    pair_kernel<<<1024, 256, 0, stream>>>(cf, labels, ws);
    final_kernel<<<16, 256, 0, stream>>>(ws, out);
}